// Round 13
// baseline (385.990 us; speedup 1.0000x reference)
//
#include <hip/hip_runtime.h>
#include <math.h>

namespace {
constexpr int B_  = 64;
constexpr int T_  = 1380;
constexpr int XD_ = 96;
constexpr int HD_ = 192;
constexpr int CN_ = 345;
constexpr int CP_ = 384;                       // padded CN
constexpr int TP_ = 1392;                      // padded T for Hth rows
constexpr int TP2_ = 1408;                     // padded T for k12 K-dim (22*64)
constexpr int TH_ = 690;                       // T/2 (u-split in k3)
constexpr float SCALE_ = 0.00736569563735987f; // 1/sqrt(96*192)
}

typedef __attribute__((ext_vector_type(8))) short bf16x8;
typedef __attribute__((ext_vector_type(4))) float f32x4;
typedef unsigned short u16;
typedef unsigned int   u32;

__device__ __forceinline__ u16 f2bf(float f) {
    union { float f; u32 u; } c; c.f = f;
    u32 r = (c.u + 0x7fffu + ((c.u >> 16) & 1u)) >> 16;
    return (u16)r;
}
__device__ __forceinline__ float bf2f(u16 s) {
    union { u32 u; float f; } c; c.u = ((u32)s) << 16;
    return c.f;
}

// 16-lane (DPP row) rotate reductions — VALU, not DS pipe (vs __shfl_xor).
__device__ __forceinline__ float red16_max(float v) {
    int ti;
    ti = __builtin_amdgcn_update_dpp(0, __builtin_bit_cast(int, v), 0x128, 0xf, 0xf, true);
    v = fmaxf(v, __builtin_bit_cast(float, ti));
    ti = __builtin_amdgcn_update_dpp(0, __builtin_bit_cast(int, v), 0x124, 0xf, 0xf, true);
    v = fmaxf(v, __builtin_bit_cast(float, ti));
    ti = __builtin_amdgcn_update_dpp(0, __builtin_bit_cast(int, v), 0x122, 0xf, 0xf, true);
    v = fmaxf(v, __builtin_bit_cast(float, ti));
    ti = __builtin_amdgcn_update_dpp(0, __builtin_bit_cast(int, v), 0x121, 0xf, 0xf, true);
    v = fmaxf(v, __builtin_bit_cast(float, ti));
    return v;
}
__device__ __forceinline__ float red16_sum(float v) {
    int ti;
    ti = __builtin_amdgcn_update_dpp(0, __builtin_bit_cast(int, v), 0x128, 0xf, 0xf, true);
    v += __builtin_bit_cast(float, ti);
    ti = __builtin_amdgcn_update_dpp(0, __builtin_bit_cast(int, v), 0x124, 0xf, 0xf, true);
    v += __builtin_bit_cast(float, ti);
    ti = __builtin_amdgcn_update_dpp(0, __builtin_bit_cast(int, v), 0x122, 0xf, 0xf, true);
    v += __builtin_bit_cast(float, ti);
    ti = __builtin_amdgcn_update_dpp(0, __builtin_bit_cast(int, v), 0x121, 0xf, 0xf, true);
    v += __builtin_bit_cast(float, ti);
    return v;
}

// ---------------------------------------------------------------------------
// K0all: ALL prep work in one launch.  blockIdx ranges:
//   [0,4224)       H prep   (22 x 3 x 64 tiles of 64u x 64h)
//   [4224,5632)    X prep   (22 x 64 tiles of 64t x 96x)
//   [5632,6760)    W2 + W1  (1128 x 256 = 288,768 tasks, exact)
// Block 5632 additionally zeroes the 128 merge tickets (re-poison per
// replay; ordered before k3 by the kernel boundary).
// ---------------------------------------------------------------------------
__global__ __launch_bounds__(256) void k0_all(const float* __restrict__ Hg,
                                              u16* __restrict__ Hh,
                                              u16* __restrict__ Hl,
                                              u16* __restrict__ Hth,
                                              const float* __restrict__ Xg,
                                              u16* __restrict__ Xth,
                                              u16* __restrict__ Xtl,
                                              const float* __restrict__ W2g,
                                              u16* __restrict__ W2h,
                                              u16* __restrict__ W2l,
                                              const float* __restrict__ W1g,
                                              u16* __restrict__ W1th,
                                              u16* __restrict__ W1tl,
                                              u32* __restrict__ Tk) {
    __shared__ __align__(16) u16 sb[2][96][72];   // 27,648 B
    const int tid = threadIdx.x;
    const int L = blockIdx.x;

    if (L < 4224) {
        // ---------------- H prep: tile (u0, h0, b) ----------------
        const int bx = L % 22, by = (L / 22) % 3, b = L / 66;
        const int u0 = bx * 64, h0 = by * 64;
        u16 (*til)[72] = sb[0];                   // [64][72] used
#pragma unroll
        for (int i = 0; i < 2; i++) {
            int task = i * 256 + tid;             // 0..511
            int r = task >> 3;                    // u row 0..63
            int g = task & 7;                     // h group of 8
            int u = u0 + r;
            float4 va = make_float4(0.f, 0.f, 0.f, 0.f), vb = va;
            if (u < T_) {
                const float* p = Hg + ((size_t)b * T_ + u) * HD_ + h0 + g * 8;
                va = *(const float4*)p;
                vb = *(const float4*)(p + 4);
            }
            float f[8] = {va.x, va.y, va.z, va.w, vb.x, vb.y, vb.z, vb.w};
            u16 hi[8], lo[8];
#pragma unroll
            for (int k = 0; k < 8; k++) {
                hi[k] = f2bf(f[k]);
                lo[k] = f2bf(f[k] - bf2f(hi[k]));
            }
            if (u < T_) {
                size_t base = ((size_t)b * T_ + u) * HD_ + h0 + g * 8;
                *(uint4*)(Hh + base) = *(const uint4*)hi;
                *(uint4*)(Hl + base) = *(const uint4*)lo;
            }
            const int rs = r ^ (g * 8);           // XOR swizzle ((h>>3)&7 == g)
#pragma unroll
            for (int k = 0; k < 8; k++) til[g * 8 + k][rs] = hi[k];
        }
        __syncthreads();
#pragma unroll
        for (int i = 0; i < 2; i++) {
            int task = i * 256 + tid;             // 0..511
            int hh = task >> 3;                   // h row 0..63
            int ug = task & 7;                    // logical u group of 8
            int q  = ug ^ (hh >> 3);              // physical chunk
            int ub = u0 + ug * 8;
            uint4 v = *(const uint4*)&til[hh][q * 8];
            u16* dst = Hth + ((size_t)b * HD_ + h0 + hh) * TP_ + ub;
            if (ub + 8 <= T_) {
                *(uint4*)dst = v;
            } else if (ub < TP_) {
                const u16* pv = (const u16*)&v;
#pragma unroll
                for (int k = 0; k < 8; k++)
                    if (ub + k < TP_) dst[k] = (ub + k < T_) ? pv[k] : (u16)0;
            }
        }
    } else if (L < 5632) {
        // ---------------- X prep: tile (t0, b) ----------------
        const int j = L - 4224;
        const int t0 = (j % 22) * 64, b = j / 22;
        u16 (*tih)[72] = sb[0];
        u16 (*tlo)[72] = sb[1];
#pragma unroll
        for (int i = 0; i < 6; i++) {
            int task = i * 256 + tid;             // 0..1535
            int r = task / 24, xg = task % 24;    // r: t-row, xg: x group of 4
            float4 v = make_float4(0.f, 0.f, 0.f, 0.f);
            if (t0 + r < T_)
                v = *(const float4*)(Xg + ((size_t)b * T_ + t0 + r) * XD_ + xg * 4);
            float f[4] = {v.x, v.y, v.z, v.w};
            const int rs = r ^ (((xg >> 1) & 7) * 8);   // (x>>3)&7 == (xg>>1)&7
#pragma unroll
            for (int k = 0; k < 4; k++) {
                u16 hi = f2bf(f[k]);
                tih[xg * 4 + k][rs] = hi;
                tlo[xg * 4 + k][rs] = f2bf(f[k] - bf2f(hi));
            }
        }
        __syncthreads();
#pragma unroll
        for (int i = 0; i < 6; i++) {
            int id = i * 256 + tid;
            int buf = (id >= 768);
            int cid = buf ? id - 768 : id;
            int x = cid >> 3, col = cid & 7;
            int q = col ^ ((x >> 3) & 7);
            uint4 v = *(const uint4*)&(buf ? tlo : tih)[x][q * 8];
            u16* dst = (buf ? Xtl : Xth) + ((size_t)b * XD_ + x) * TP2_ + t0 + col * 8;
            *(uint4*)dst = v;
        }
    } else {
        // ---------------- W2 + W1 prep (exact 1128 x 256 tasks) ----------------
        const int j = L - 5632;                   // 0..1127
        if (j == 0 && tid < 128) Tk[tid] = 0;     // merge tickets: re-poison
        const int i = j * 256 + tid;              // 0..288,767
        const int n2 = CP_ * (TP2_ / 2);          // 270,336
        if (i < n2) {
            int c = i / (TP2_ / 2), tc = i % (TP2_ / 2);
            int t = tc * 2;
            float v0 = 0.f, v1 = 0.f;
            if (c < CN_) {
                if (t < T_)     v0 = W2g[(size_t)c * T_ + t];
                if (t + 1 < T_) v1 = W2g[(size_t)c * T_ + t + 1];
            }
            u16 h0 = f2bf(v0), h1 = f2bf(v1);
            u16 l0 = f2bf(v0 - bf2f(h0)), l1 = f2bf(v1 - bf2f(h1));
            ((u32*)W2h)[i] = (u32)h0 | ((u32)h1 << 16);
            ((u32*)W2l)[i] = (u32)l0 | ((u32)l1 << 16);
        } else {
            int i1 = i - n2;                      // 0..18,431
            int h = i1 / XD_, x = i1 % XD_;
            float v = W1g[(size_t)x * HD_ + h];
            u16 hi = f2bf(v);
            W1th[i1] = hi;
            W1tl[i1] = f2bf(v - bf2f(hi));
        }
    }
}

// ---------------------------------------------------------------------------
// K12: unchanged (passed; gld_lds + counted vmcnt + dbuf).
// ---------------------------------------------------------------------------
__global__ __launch_bounds__(256, 1) void k12_mfma(const u16* __restrict__ W2h,
                                                   const u16* __restrict__ W2l,
                                                   const u16* __restrict__ Xth,
                                                   const u16* __restrict__ Xtl,
                                                   const u16* __restrict__ W1th,
                                                   const u16* __restrict__ W1tl,
                                                   u32* __restrict__ Ysi) {
    __shared__ __align__(16) u16 smem[49152];   // 96 KB = 2 bufs x 4 arrays x 96x64
    float* sZ = (float*)smem;                   // phase 2: 96 x 100 fp32 (38.4 KB, buf0 only)

    const int tid  = threadIdx.x;
    const int lane = tid & 63;
    const int w    = tid >> 6;            // 0..3: wave id == staging array id
    const int tx   = lane & 15;
    const int quad = lane >> 4;
    const int wr   = w >> 1;              // c-half (48 rows)
    const int wc2  = w & 1;               // x-half (48 cols)
    const int L    = blockIdx.x;
    const int xcd  = L & 7;
    const int slot = L >> 3;              // 0..31
    const int b    = xcd * 8 + (slot >> 2);
    const int c0   = (slot & 3) * 96;

    const u16* gsrc;
    size_t rowstart;
    if (w == 0)      { gsrc = W2h; rowstart = (size_t)c0; }
    else if (w == 1) { gsrc = W2l; rowstart = (size_t)c0; }
    else if (w == 2) { gsrc = Xth; rowstart = (size_t)b * XD_; }
    else             { gsrc = Xtl; rowstart = (size_t)b * XD_; }
    const int jg = (lane & 7) ^ ((lane >> 3) & 7);   // pre-swizzled source group

#define STAGE(bufsel, kk)                                                         \
    {                                                                             \
        u16* lb = smem + (bufsel) * 24576 + w * 6144;                             \
        _Pragma("unroll")                                                         \
        for (int i_ = 0; i_ < 12; i_++) {                                         \
            int row_ = i_ * 8 + (lane >> 3);                                      \
            const u16* gp_ = gsrc + (rowstart + row_) * TP2_ + (kk) + jg * 8;     \
            __builtin_amdgcn_global_load_lds(                                     \
                (const __attribute__((address_space(1))) u32*)(const void*)gp_,   \
                (__attribute__((address_space(3))) u32*)(void*)(lb + i_ * 512),   \
                16, 0, 0);                                                        \
        }                                                                         \
    }

    f32x4 accZ[3][3];
#pragma unroll
    for (int i = 0; i < 3; i++)
#pragma unroll
        for (int j = 0; j < 3; j++) accZ[i][j] = (f32x4){0.f, 0.f, 0.f, 0.f};

    STAGE(0, 0);
    for (int s = 0; s < 22; s++) {
        __builtin_amdgcn_sched_barrier(0);
        if (s < 21) {
            STAGE((s + 1) & 1, (s + 1) * 64);
            asm volatile("s_waitcnt vmcnt(12)" ::: "memory");  // cur tile landed
        } else {
            asm volatile("s_waitcnt vmcnt(0)" ::: "memory");
        }
        __builtin_amdgcn_s_barrier();
        __builtin_amdgcn_sched_barrier(0);
        const u16* bufp = smem + (s & 1) * 24576;
#pragma unroll
        for (int ks2 = 0; ks2 < 2; ks2++) {
            const int G = ks2 * 4 + quad;
            bf16x8 ah[3], al[3], bh3[3], bl3[3];
#pragma unroll
            for (int am = 0; am < 3; am++) {
                int row = wr * 48 + am * 16 + tx;
                int off = row * 64 + (G ^ (row & 7)) * 8;
                ah[am] = *(const bf16x8*)(bufp + off);
                al[am] = *(const bf16x8*)(bufp + 6144 + off);
            }
#pragma unroll
            for (int bn = 0; bn < 3; bn++) {
                int row = wc2 * 48 + bn * 16 + tx;
                int off = row * 64 + (G ^ (row & 7)) * 8;
                bh3[bn] = *(const bf16x8*)(bufp + 12288 + off);
                bl3[bn] = *(const bf16x8*)(bufp + 18432 + off);
            }
#pragma unroll
            for (int am = 0; am < 3; am++)
#pragma unroll
                for (int bn = 0; bn < 3; bn++) {
                    accZ[am][bn] = __builtin_amdgcn_mfma_f32_16x16x32_bf16(ah[am], bh3[bn], accZ[am][bn], 0, 0, 0);
                    accZ[am][bn] = __builtin_amdgcn_mfma_f32_16x16x32_bf16(ah[am], bl3[bn], accZ[am][bn], 0, 0, 0);
                    accZ[am][bn] = __builtin_amdgcn_mfma_f32_16x16x32_bf16(al[am], bh3[bn], accZ[am][bn], 0, 0, 0);
                }
        }
        asm volatile("s_waitcnt lgkmcnt(0)" ::: "memory");
        __builtin_amdgcn_sched_barrier(0);
        __builtin_amdgcn_s_barrier();
    }
#undef STAGE

    __builtin_amdgcn_sched_barrier(0);
#pragma unroll
    for (int am = 0; am < 3; am++)
#pragma unroll
        for (int bn = 0; bn < 3; bn++)
#pragma unroll
            for (int r = 0; r < 4; r++)
                sZ[(wr * 48 + am * 16 + quad * 4 + r) * 100 + wc2 * 48 + bn * 16 + tx] = accZ[am][bn][r];
    __syncthreads();

    bf16x8 A2h[3][3], A2l[3][3];
#pragma unroll
    for (int am = 0; am < 3; am++)
#pragma unroll
        for (int ks = 0; ks < 3; ks++) {
            const float* zrow = sZ + (wr * 48 + am * 16 + tx) * 100 + ks * 32 + quad * 8;
            bf16x8 vh, vl;
#pragma unroll
            for (int j = 0; j < 8; j++) {
                float v = zrow[j];
                u16 hi = f2bf(v);
                vh[j] = (short)hi;
                vl[j] = (short)f2bf(v - bf2f(hi));
            }
            A2h[am][ks] = vh; A2l[am][ks] = vl;
        }

    f32x4 accY[3][6];
#pragma unroll
    for (int i = 0; i < 3; i++)
#pragma unroll
        for (int j = 0; j < 6; j++) accY[i][j] = (f32x4){0.f, 0.f, 0.f, 0.f};
#pragma unroll
    for (int hn = 0; hn < 6; hn++) {
        const int hrow = wc2 * 96 + hn * 16 + tx;
#pragma unroll
        for (int ks = 0; ks < 3; ks++) {
            bf16x8 bh = *(const bf16x8*)(W1th + (size_t)hrow * XD_ + ks * 32 + quad * 8);
            bf16x8 bl = *(const bf16x8*)(W1tl + (size_t)hrow * XD_ + ks * 32 + quad * 8);
#pragma unroll
            for (int am = 0; am < 3; am++) {
                accY[am][hn] = __builtin_amdgcn_mfma_f32_16x16x32_bf16(A2h[am][ks], bh, accY[am][hn], 0, 0, 0);
                accY[am][hn] = __builtin_amdgcn_mfma_f32_16x16x32_bf16(A2h[am][ks], bl, accY[am][hn], 0, 0, 0);
                accY[am][hn] = __builtin_amdgcn_mfma_f32_16x16x32_bf16(A2l[am][ks], bh, accY[am][hn], 0, 0, 0);
            }
        }
    }

#pragma unroll
    for (int am = 0; am < 3; am++)
#pragma unroll
        for (int r = 0; r < 4; r++) {
            int c = c0 + wr * 48 + am * 16 + quad * 4 + r;
            if (c < CN_) {
                size_t base = ((size_t)b * CN_ + c) * HD_;
#pragma unroll
                for (int hn = 0; hn < 6; hn++) {
                    float y = SCALE_ * accY[am][hn][r];
                    u16 hi = f2bf(y);
                    u16 lo = f2bf(y - bf2f(hi));
                    Ysi[base + wc2 * 96 + hn * 16 + tx] = (u32)hi | ((u32)lo << 16);
                }
            }
        }
}

// ---------------------------------------------------------------------------
// K3: round-8 symmetric 12-wave version + FUSED MERGE epilogue.  Each (b,ct)
// tile is produced by exactly 2 blocks (sp=0/1, provably same XCD).  Every
// block writes its Op/Ml/Ll partial, fences, takes an atomic ticket; the
// second finisher reads the other half (fence-atomic-fence sync) and writes
// the final output from its live accO registers.  No spinning; re-poisoned
// tickets come from k0_all each replay.
// ---------------------------------------------------------------------------
__global__ __launch_bounds__(768, 3) void k3_mfma(const u32* __restrict__ Ysi,
                                                  const u16* __restrict__ Hh,
                                                  const u16* __restrict__ Hl,
                                                  const u16* __restrict__ Hth,
                                                  float* __restrict__ Op,
                                                  float* __restrict__ Ml,
                                                  float* __restrict__ Ll,
                                                  float* __restrict__ out,
                                                  u32* __restrict__ Tk) {
    __shared__ __align__(16) u16 smem[44544];   // 89,088 B: 73,728 H-dbuf + 15,360 sP

    const int tid  = threadIdx.x;
    const int lane = tid & 63;
    const int w    = tid >> 6;            // 0..11
    const int tx   = lane & 15;
    const int quad = lane >> 4;
    const int L    = blockIdx.x;
    const int xcd  = L & 7;
    const int slot = L >> 3;              // 0..31
    const int gp   = xcd * 16 + (slot >> 1);   // (b,sp) pair, 0..127
    const int ct   = slot & 1;                 // c-tile half (192 rows)
    const int b    = gp >> 1;
    const int sp   = gp & 1;
    const int c0   = ct * 192;
    const int us   = sp * TH_, ue = us + TH_;

    // ---- A-operand from interleaved Ysi (unpack once)
    bf16x8 Ah[6], Al[6];
    const int ar = c0 + w * 16 + tx;
    if (ar < CN_) {
        const u32* yi = Ysi + ((size_t)b * CN_ + ar) * HD_;
#pragma unroll
        for (int ks = 0; ks < 6; ks++) {
            u32 vv[8];
            *(uint4*)&vv[0] = *(const uint4*)(yi + ks * 32 + quad * 8);
            *(uint4*)&vv[4] = *(const uint4*)(yi + ks * 32 + quad * 8 + 4);
            bf16x8 hh, ll;
#pragma unroll
            for (int j = 0; j < 8; j++) {
                hh[j] = (short)(vv[j] & 0xffffu);
                ll[j] = (short)(vv[j] >> 16);
            }
            Ah[ks] = hh; Al[ks] = ll;
        }
    } else {
#pragma unroll
        for (int ks = 0; ks < 6; ks++) { Ah[ks] = (bf16x8)0; Al[ks] = (bf16x8)0; }
    }

    float m_s[4], l_s[4];
    f32x4 accO[12];
#pragma unroll
    for (int r = 0; r < 4; r++) { m_s[r] = -1e30f; l_s[r] = 0.f; }
#pragma unroll
    for (int j = 0; j < 12; j++) accO[j] = (f32x4){0.f, 0.f, 0.f, 0.f};

    // ---- per-lane staging descriptors: 36 gld_lds/iter, 3 per wave.
    const char* srcp[3];
    u32 off0[3];
    const u32 incw = (u32)__builtin_amdgcn_readfirstlane((w < 8) ? (32 * HD_ * 2) : 64);
#pragma unroll
    for (int j = 0; j < 3; j++) {
        int k = w * 3 + j;
        u32 o;
        if (k < 24) {
            int arr = (k < 12) ? 0 : 1;
            int ii  = k - arr * 12;
            int cid = ii * 64 + lane;          // 0..767
            int u   = cid / 24, c1 = cid % 24;
            int c   = (c1 & ~7) | ((c1 & 7) ^ ((u >> 1) & 7));
            const u16* basep = (arr == 0 ? Hh : Hl) + (size_t)b * T_ * HD_;
            srcp[j] = (const char*)basep + ((size_t)(us + u) * HD_ + c * 8) * 2;
            o = (u32)(arr * 24576 + ii * 1024);
        } else {
            int ii  = k - 24;
            int cid = ii * 64 + lane;          // 0..767
            int h   = cid >> 2, c2 = cid & 3;
            int c   = c2 ^ ((h >> 2) & 3);
            const u16* basep = Hth + (size_t)b * HD_ * TP_;
            srcp[j] = (const char*)basep + ((size_t)h * TP_ + us + c * 8) * 2;
            o = (u32)(49152 + ii * 1024);
        }
        off0[j] = (u32)__builtin_amdgcn_readfirstlane((int)o);
    }

#define STAGE3(bufsel)                                                            \
    {                                                                             \
        _Pragma("unroll")                                                         \
        for (int j_ = 0; j_ < 3; j_++) {                                          \
            __builtin_amdgcn_global_load_lds(                                     \
                (const __attribute__((address_space(1))) u32*)(const void*)srcp[j_], \
                (__attribute__((address_space(3))) u32*)(void*)((char*)smem + off0[j_] + (bufsel) * 12288), \
                16, 0, 0);                                                        \
            srcp[j_] += incw;                                                     \
        }                                                                         \
    }

    u16* sPb = smem + 36864;                   // 192 x 40 u16 (byte 73,728)

    STAGE3(0);                                  // tile 0 -> buf 0
    for (int t = 0; t < 22; t++) {
        const int u0  = us + t * 32;
        const int buf = t & 1;
        __builtin_amdgcn_sched_barrier(0);
        if (t < 21) {
            STAGE3(buf ^ 1);                    // tile t+1 -> other buf
            asm volatile("s_waitcnt vmcnt(3)" ::: "memory");   // tile t landed
        } else {
            asm volatile("s_waitcnt vmcnt(0)" ::: "memory");
        }
        __builtin_amdgcn_s_barrier();
        __builtin_amdgcn_sched_barrier(0);

        const u16* Hhb = smem + buf * 6144;
        const u16* Hlb = smem + 12288 + buf * 6144;
        const u16* Htb = smem + 24576 + buf * 6144;

        // ---- GEMM1: S[c][u], K=192, split-bf16 (hi*hi + hi*lo + lo*hi)
        f32x4 s0a = {0.f, 0.f, 0.f, 0.f}, s1a = {0.f, 0.f, 0.f, 0.f};
        f32x4 s0b = {0.f, 0.f, 0.f, 0.f}, s1b = {0.f, 0.f, 0.f, 0.f};
        const int xr = (tx >> 1) & 7;           // same for row tx and 16+tx
        __builtin_amdgcn_s_setprio(1);
#pragma unroll
        for (int ks = 0; ks < 6; ks++) {
            const int cc = ks * 4 + quad;
            const int cs = (cc & ~7) | ((cc & 7) ^ xr);
            const int ro0 = tx * 192 + cs * 8;
            const int ro1 = (16 + tx) * 192 + cs * 8;
            bf16x8 bh0 = *(const bf16x8*)(Hhb + ro0);
            bf16x8 bl0 = *(const bf16x8*)(Hlb + ro0);
            bf16x8 bh1 = *(const bf16x8*)(Hhb + ro1);
            bf16x8 bl1 = *(const bf16x8*)(Hlb + ro1);
            s0a = __builtin_amdgcn_mfma_f32_16x16x32_bf16(Ah[ks], bh0, s0a, 0, 0, 0);
            s1a = __builtin_amdgcn_mfma_f32_16x16x32_bf16(Ah[ks], bl0, s1a, 0, 0, 0);
            s1a = __builtin_amdgcn_mfma_f32_16x16x32_bf16(Al[ks], bh0, s1a, 0, 0, 0);
            s0b = __builtin_amdgcn_mfma_f32_16x16x32_bf16(Ah[ks], bh1, s0b, 0, 0, 0);
            s1b = __builtin_amdgcn_mfma_f32_16x16x32_bf16(Ah[ks], bl1, s1b, 0, 0, 0);
            s1b = __builtin_amdgcn_mfma_f32_16x16x32_bf16(Al[ks], bh1, s1b, 0, 0, 0);
        }
        __builtin_amdgcn_s_setprio(0);
        float sv0[4], sv1[4];
        const bool okA = (u0 + tx) < ue, okB = (u0 + 16 + tx) < ue;
#pragma unroll
        for (int r = 0; r < 4; r++) {
            sv0[r] = okA ? (s0a[r] + s1a[r]) : -1e30f;
            sv1[r] = okB ? (s0b[r] + s1b[r]) : -1e30f;
        }

        // ---- online softmax; 16-lane reductions via DPP (VALU, no DS)
        float alpha[4];
#pragma unroll
        for (int r = 0; r < 4; r++) {
            float mx = red16_max(fmaxf(sv0[r], sv1[r]));
            float mn = fmaxf(m_s[r], mx);
            alpha[r] = __expf(m_s[r] - mn);
            float p0 = __expf(sv0[r] - mn);
            float p1 = __expf(sv1[r] - mn);
            sPb[(w * 16 + quad * 4 + r) * 40 + tx]      = f2bf(p0);
            sPb[(w * 16 + quad * 4 + r) * 40 + 16 + tx] = f2bf(p1);
            float s = red16_sum(p0 + p1);
            l_s[r] = l_s[r] * alpha[r] + s;
            m_s[r] = mn;
        }
        f32x4 alv = {alpha[0], alpha[1], alpha[2], alpha[3]};
#pragma unroll
        for (int j = 0; j < 12; j++) accO[j] *= alv;

        // ---- PV: O += P * H, K=32.  sP rows are wave-private (in-order DS).
        bf16x8 pa = *(const bf16x8*)(sPb + (w * 16 + tx) * 40 + quad * 8);
        const int ctq = quad ^ ((tx >> 2) & 3);
        __builtin_amdgcn_s_setprio(1);
#pragma unroll
        for (int j = 0; j < 12; j++) {
            bf16x8 hb = *(const bf16x8*)(Htb + (j * 16 + tx) * 32 + ctq * 8);
            accO[j] = __builtin_amdgcn_mfma_f32_16x16x32_bf16(pa, hb, accO[j], 0, 0, 0);
        }
        __builtin_amdgcn_s_setprio(0);

        // all LDS reads of buf done before any wave stages into it next iter
        asm volatile("s_waitcnt lgkmcnt(0)" ::: "memory");
        __builtin_amdgcn_sched_barrier(0);
        __builtin_amdgcn_s_barrier();
    }
#undef STAGE3

    // ---- write own partial (Op, M, L)
#pragma unroll
    for (int r = 0; r < 4; r++) {
        int c = c0 + w * 16 + quad * 4 + r;
        if (c < CN_) {
            float* orow = Op + (((size_t)sp * B_ + b) * CN_ + c) * HD_;
#pragma unroll
            for (int j = 0; j < 12; j++) orow[j * 16 + tx] = accO[j][r];
            if (tx == 0) {
                size_t mi = ((size_t)sp * B_ + b) * CN_ + c;
                Ml[mi] = m_s[r];
                Ll[mi] = l_s[r];
            }
        }
    }

    // ---- fused merge: second finisher per (b,ct) combines halves
    __threadfence();                       // release: partials visible
    __syncthreads();                       // all threads' stores fenced
    if (tid == 0) ((u32*)smem)[0] = atomicAdd(&Tk[b * 2 + ct], 1u);
    __syncthreads();
    const u32 old = ((u32*)smem)[0];
    if (old == 1) {
        __threadfence();                   // acquire: see other half's data
        const int spo = sp ^ 1;
#pragma unroll
        for (int r = 0; r < 4; r++) {
            int c = c0 + w * 16 + quad * 4 + r;
            if (c < CN_) {
                size_t mio = ((size_t)spo * B_ + b) * CN_ + c;
                float mo = Ml[mio], lo2 = Ll[mio];
                float M  = fmaxf(m_s[r], mo);
                float e0 = __expf(m_s[r] - M), e1 = __expf(mo - M);
                float inv = 1.0f / (l_s[r] * e0 + lo2 * e1);
                const float* oro = Op + mio * HD_;
                float* dst = out + ((size_t)b * CN_ + c) * HD_;
#pragma unroll
                for (int j = 0; j < 12; j++) {
                    float o1 = oro[j * 16 + tx];
                    dst[j * 16 + tx] = (accO[j][r] * e0 + o1 * e1) * inv;
                }
            }
        }
    }
}

// ---------------------------------------------------------------------------
extern "C" void kernel_launch(void* const* d_in, const int* in_sizes, int n_in,
                              void* d_out, int out_size, void* d_ws, size_t ws_size,
                              hipStream_t stream) {
    const float* X  = (const float*)d_in[0];
    const float* H  = (const float*)d_in[1];
    const float* W1 = (const float*)d_in[2];
    const float* W2 = (const float*)d_in[3];
    float* out = (float*)d_out;

    char* ws = (char*)d_ws;
    u32*   Ysi  = (u32*)(ws);                    //  16,957,440 (interleaved hi|lo)
    u16*   Hh   = (u16*)(ws + 16957440);         //  33,914,880
    u16*   Hl   = (u16*)(ws + 50872320);         //  33,914,880
    u16*   Hth  = (u16*)(ws + 84787200);         //  34,209,792
    u16*   Xth  = (u16*)(ws + 118996992);        //  17,301,504  (aliased by Op later)
    u16*   Xtl  = (u16*)(ws + 136298496);        //  17,301,504
    float* Op   = (float*)(ws + 118996992);      //  33,914,880  (aliases Xth+Xtl; k12 done first)
    u16*   W2h  = (u16*)(ws + 153600000);        //   1,081,344
    u16*   W2l  = (u16*)(ws + 154681344);        //   1,081,344
    u16*   W1th = (u16*)(ws + 155762688);        //      36,864
    u16*   W1tl = (u16*)(ws + 155799552);        //      36,864
    float* Ml   = (float*)(ws + 155836416);      //     176,640
    float* Ll   = (float*)(ws + 156013056);      //     176,640
    u32*   Tk   = (u32*)(ws + 156189696);        //         512  -> end 156,190,208

    k0_all  <<<dim3(6760),      256, 0, stream>>>(H, Hh, Hl, Hth,
                                                  X, Xth, Xtl,
                                                  W2, W2h, W2l,
                                                  W1, W1th, W1tl, Tk);
    k12_mfma<<<dim3(256),       256, 0, stream>>>(W2h, W2l, Xth, Xtl, W1th, W1tl, Ysi);
    k3_mfma <<<dim3(256),       768, 0, stream>>>(Ysi, Hh, Hl, Hth, Op, Ml, Ll, out, Tk);
}